// Round 6
// baseline (317.555 us; speedup 1.0000x reference)
//
#include <hip/hip_runtime.h>
#include <stdint.h>
#include <type_traits>

// ---------------- problem constants ----------------
#define CIN   256
#define COUT  256
#define HH    56
#define WW    56
#define HW    3136          // 56*56
#define BATCH 32
#define NPIX  (BATCH*HW)    // 100352 = 784 * 128 exactly
#define PH    58
#define PW    58
#define PPIX  (PH*PW)       // 3364
#define KTOT  2304          // 9 taps * 256 cin
#define BKB   128           // K-block in bytes (i8 elems) = half a tap
#define NKIT  (KTOT/BKB)    // 18

typedef int8_t  i8;
typedef int     intx4  __attribute__((ext_vector_type(4)));
typedef int8_t  i8x16  __attribute__((ext_vector_type(16)));
typedef short   short8 __attribute__((ext_vector_type(8)));
typedef float   floatx4 __attribute__((ext_vector_type(4)));

// -------- global->LDS 16B async copy (offset arg MUST stay 0: it shifts the
// LDS destination too — R4 failed on this) -----------------------------------
__device__ __forceinline__ void gload_lds16(const i8* g, void* lds_base) {
    __builtin_amdgcn_global_load_lds(
        (const __attribute__((address_space(1))) void*)g,
        (__attribute__((address_space(3))) void*)lds_base,
        16, 0, 0);
}

// ---------------------------------------------------------------------------
// Kernel 1: weight prep. scale[o]=mean|w[o]|. Writes sign(w) DIRECTLY in MFMA
// B-fragment order: bfr[((seg*18+kb)*2+kk)*4+in][lane][16B], where the conv
// wave (seg = nt*2+wn) loads 1 KB coalesced chunks. Mapping derived from the
// R5 (passing) LDS read path: lane l holds B[row=in*16+(l&15)][k-chunk l>>4].
// Also zero-inits BN-stat accumulators.
// ---------------------------------------------------------------------------
__global__ __launch_bounds__(256) void prep_w(const float* __restrict__ w,
                                              i8* __restrict__ bfr,
                                              float* __restrict__ scale,
                                              float* __restrict__ bnsum,
                                              float* __restrict__ bnsumsq) {
    int o = blockIdx.x;
    int i = threadIdx.x;
    const float* wrow = w + (size_t)o * KTOT + (size_t)i * 9;   // OIHW
    int seg = o >> 6;           // (nt*2 + wn)
    int inq = (o >> 4) & 3;     // in-tile
    int n15 = o & 15;
    float asum = 0.f;
#pragma unroll
    for (int t = 0; t < 9; ++t) {
        float v = wrow[t];
        asum += fabsf(v);
        i8 s = (v > 0.f) ? (i8)1 : ((v < 0.f) ? (i8)(-1) : (i8)0);
        int k  = t * 256 + i;
        int kb = k >> 7;
        int kk = (k >> 6) & 1;
        int a  = (k >> 4) & 3;
        int b  = k & 15;
        int lane = a * 16 + n15;
        bfr[((((size_t)seg * 18 + kb) * 2 + kk) * 4 + inq) * 1024 + lane * 16 + b] = s;
    }
    for (int off = 32; off > 0; off >>= 1) asum += __shfl_down(asum, off);
    __shared__ float red[4];
    if ((threadIdx.x & 63) == 0) red[threadIdx.x >> 6] = asum;
    __syncthreads();
    if (threadIdx.x == 0) {
        scale[o]   = (red[0] + red[1] + red[2] + red[3]) * (1.f / (float)KTOT);
        bnsum[o]   = 0.f;
        bnsumsq[o] = 0.f;
    }
}

// ---------------------------------------------------------------------------
// Kernel 2: zero the 1-pixel border of the padded NHWC int8 sign tensor.
// ---------------------------------------------------------------------------
__global__ __launch_bounds__(256) void zero_border(i8* __restrict__ xs) {
    int n  = blockIdx.x / PH;
    int pr = blockIdx.x % PH;
    int* row = (int*)(xs + ((size_t)n * PPIX + (size_t)pr * PW) * CIN);
    if (pr == 0 || pr == PH - 1) {
        for (int idx = threadIdx.x; idx < PW * CIN / 4; idx += 256) row[idx] = 0;
    } else {
        if (threadIdx.x < 64)       row[threadIdx.x] = 0;                       // col 0
        else if (threadIdx.x < 128) row[(PW - 1) * (CIN / 4) + threadIdx.x - 64] = 0; // col 57
    }
}

// ---------------------------------------------------------------------------
// Kernel 3: binarize + NCHW->padded-NHWC, int8 out. LDS-FREE.
// grid (49, 4, 32): 64-pixel x 64-cin tiles. Thread t: 4 pixels (t&15 group),
// 4 cins (t>>4 quad). float4 reads (256B contig per 16-lane group), pack sign
// bytes in regs, 4B dword stores (16 x 64B segments per inst).
// ---------------------------------------------------------------------------
__global__ __launch_bounds__(256) void binarize(const float* __restrict__ x,
                                                i8* __restrict__ xs) {
    int p0 = blockIdx.x * 64;
    int c0 = blockIdx.y * 64;
    int n  = blockIdx.z;
    int t  = threadIdx.x;
    int pg = t & 15;          // pixel group: p0 + 4*pg .. +3
    int cq = t >> 4;          // cin quad:   c0 + 4*cq .. +3
    const float* xin = x + (size_t)n * CIN * HW + (size_t)(c0 + 4 * cq) * HW + p0 + 4 * pg;
    int packed[4] = {0, 0, 0, 0};
#pragma unroll
    for (int e = 0; e < 4; ++e) {
        floatx4 v = *(const floatx4*)(xin + (size_t)e * HW);
#pragma unroll
        for (int pp = 0; pp < 4; ++pp) {
            int s = (v[pp] > 0.f) ? 1 : ((v[pp] < 0.f) ? -1 : 0);
            packed[pp] |= (s & 0xff) << (8 * e);
        }
    }
#pragma unroll
    for (int pp = 0; pp < 4; ++pp) {
        int p = p0 + 4 * pg + pp;
        int h = p / WW, w = p - (p / WW) * WW;
        *(int*)&xs[((size_t)n * PPIX + (size_t)(h + 1) * PW + (w + 1)) * CIN
                   + c0 + 4 * cq] = packed[pp];
    }
}

// ---------------------------------------------------------------------------
// Kernel 4: binary conv implicit GEMM, i8 MFMA K=64.
// A: LDS double-buffered (2 x 16 KB) via global_load_lds, XOR-swizzled.
// B: NO LDS — fragment-ordered global array (bfr), coalesced 1 KB
//    global_load_dwordx4 into ping-pong registers, prefetched 1 iter ahead.
// One barrier per K-iter. Epilogue: C -> LDS (128x128 int16, 32 KB) ->
// coalesced short8 NHWC stores + per-channel atomic sum/sumsq.
// ---------------------------------------------------------------------------
__global__ __launch_bounds__(256, 2) void conv_gemm(const i8* __restrict__ xs,
                                                    const i8* __restrict__ bfr,
                                                    short* __restrict__ y,
                                                    float* __restrict__ bnsum,
                                                    float* __restrict__ bnsumsq) {
    __shared__ __align__(16) i8 smem[32768];   // A dbuf: buf b at b*16384

    int tid  = threadIdx.x;
    int lane = tid & 63;
    int wv   = tid >> 6;
    int wm   = wv & 1;        // wave row (pixels)
    int wn   = wv >> 1;       // wave col (couts)
    int mt   = blockIdx.x;
    int nt   = blockIdx.y;

    // ---- A staging source pointers (XOR-swizzled 16B chunk in 128B row) ----
    int prow = tid >> 3;
    int koff = ((tid ^ (tid >> 3)) & 7) * 16;
    const i8* aP[4];
#pragma unroll
    for (int j = 0; j < 4; ++j) {
        int P = mt * 128 + prow + 32 * j;     // global pixel
        int n = P / HW;
        int p = P - n * HW;
        int h = p / WW;
        int w = p - h * WW;
        aP[j] = xs + ((size_t)n * PPIX + (size_t)h * PW + w) * CIN + koff;
    }
    i8* aD[2][4];
#pragma unroll
    for (int b = 0; b < 2; ++b)
#pragma unroll
        for (int j = 0; j < 4; ++j)
            aD[b][j] = smem + b * 16384 + j * 4096 + wv * 1024;

    // ---- A fragment read pointers ----
    int l7  = lane & 7;
    int l15 = lane & 15;
    int lhi = lane >> 4;
    int sw0 = ((lhi ^ l7) << 4);              // kk=0 swizzled chunk offset
    int sw1 = sw0 ^ 0x40;                     // kk=1
    const i8* Ard0 = smem + (wm * 64 + l15) * BKB + sw0;
    const i8* Ard1 = smem + (wm * 64 + l15) * BKB + sw1;

    // ---- B fragment base (coalesced: lane*16 within 1 KB chunks) ----
    const i8* bW = bfr + (size_t)(nt * 2 + wn) * 18 * 8192 + lane * 16;
    intx4 bR[2][8];                            // [parity][kk*4+in]

    intx4 acc[4][4];
#pragma unroll
    for (int im = 0; im < 4; ++im)
#pragma unroll
        for (int in = 0; in < 4; ++in) acc[im][in] = intx4{0, 0, 0, 0};

    // ---- prologue: stage k=0 ----
#pragma unroll
    for (int j = 0; j < 4; ++j) gload_lds16(aP[j], aD[0][j]);
#pragma unroll
    for (int q = 0; q < 8; ++q) bR[0][q] = *(const intx4*)(bW + q * 1024);
    __syncthreads();

    auto stage = [&](auto KBC) {
        constexpr int KB  = (int)decltype(KBC)::value;
        constexpr int cur = KB & 1;
        if constexpr (KB < NKIT - 1) {
            constexpr int nb  = KB + 1;
            constexpr int nxt = nb & 1;
            constexpr int ao  = (nb / 6) * PW * CIN + (nb % 6) * 128;  // tap row/col
#pragma unroll
            for (int q = 0; q < 8; ++q)
                bR[nxt][q] = *(const intx4*)(bW + (size_t)nb * 8192 + q * 1024);
#pragma unroll
            for (int j = 0; j < 4; ++j) gload_lds16(aP[j] + ao, aD[nxt][j]);
        }
        constexpr int bufo = cur * 16384;
        intx4 af0[4], af1[4];
#pragma unroll
        for (int im = 0; im < 4; ++im) af0[im] = *(const intx4*)(Ard0 + bufo + im * 2048);
#pragma unroll
        for (int im = 0; im < 4; ++im) af1[im] = *(const intx4*)(Ard1 + bufo + im * 2048);
#pragma unroll
        for (int im = 0; im < 4; ++im)
#pragma unroll
            for (int in = 0; in < 4; ++in)
                acc[im][in] = __builtin_amdgcn_mfma_i32_16x16x64_i8(
                    af0[im], bR[cur][in], acc[im][in], 0, 0, 0);
#pragma unroll
        for (int im = 0; im < 4; ++im)
#pragma unroll
            for (int in = 0; in < 4; ++in)
                acc[im][in] = __builtin_amdgcn_mfma_i32_16x16x64_i8(
                    af1[im], bR[cur][4 + in], acc[im][in], 0, 0, 0);
        __syncthreads();
    };
#define ST(k) stage(std::integral_constant<int, k>{});
    ST(0) ST(1) ST(2) ST(3) ST(4) ST(5) ST(6) ST(7) ST(8)
    ST(9) ST(10) ST(11) ST(12) ST(13) ST(14) ST(15) ST(16) ST(17)
#undef ST

    // ---- epilogue: BN stats from regs + coalesced store via LDS transpose ----
    int colBase = nt * 128 + wn * 64 + l15;            // global cout
    short* yt = (short*)smem;                          // 128 x 128 int16, 32 KB
#pragma unroll
    for (int in = 0; in < 4; ++in) {
        int o = colBase + in * 16;
        float s1 = 0.f, s2 = 0.f;
#pragma unroll
        for (int im = 0; im < 4; ++im) {
            int r0 = wm * 64 + im * 16 + lhi * 4;      // local pixel row
#pragma unroll
            for (int rg = 0; rg < 4; ++rg) {
                int vi = acc[im][in][rg];              // exact integer count
                yt[(r0 + rg) * 128 + wn * 64 + in * 16 + l15] = (short)vi;
                float v = (float)vi;
                s1 += v;
                s2 += v * v;
            }
        }
        s1 += __shfl_xor(s1, 16); s2 += __shfl_xor(s2, 16);
        s1 += __shfl_xor(s1, 32); s2 += __shfl_xor(s2, 32);
        if (lhi == 0) {
            atomicAdd(&bnsum[o], s1);
            atomicAdd(&bnsumsq[o], s2);
        }
    }
    __syncthreads();
    // coalesced NHWC stores: 16 threads x 16B = one 128-cout half-row
#pragma unroll
    for (int pass = 0; pass < 8; ++pass) {
        int p = (tid >> 4) + 16 * pass;
        int c = tid & 15;
        *(short8*)&y[(size_t)(mt * 128 + p) * COUT + nt * 128 + c * 8] =
            *(const short8*)&yt[p * 128 + c * 8];
    }
}

// ---------------------------------------------------------------------------
// Kernel 5: fold BN into per-channel (g, c): out = relu(g*s + c)
// ---------------------------------------------------------------------------
__global__ void coeff(const float* __restrict__ bnsum, const float* __restrict__ bnsumsq,
                      const float* __restrict__ scale, const float* __restrict__ gamma,
                      const float* __restrict__ beta, float* __restrict__ kg,
                      float* __restrict__ kc) {
    int o = threadIdx.x;
    float mean = bnsum[o] * (1.f / (float)NPIX);
    float var  = fmaxf(bnsumsq[o] * (1.f / (float)NPIX) - mean * mean, 0.f);
    float sc   = scale[o];
    float inv  = rsqrtf(sc * sc * var + 1e-5f);
    float g    = gamma[o] * sc * inv;
    kg[o] = g;
    kc[o] = beta[o] - mean * g;
}

// ---------------------------------------------------------------------------
// Kernel 6: int16 NHWC -> fp32 NCHW transpose + affine + relu.
// ---------------------------------------------------------------------------
__global__ __launch_bounds__(256) void bn_out(const short* __restrict__ y,
                                              const float* __restrict__ kg,
                                              const float* __restrict__ kc,
                                              float* __restrict__ out) {
    __shared__ float lds[64 * 65];   // [pix][ch], stride 65
    int p0 = blockIdx.x * 64;
    int o0 = blockIdx.y * 64;
    int n  = blockIdx.z;
    int t  = threadIdx.x;
    int cch = t & 7;
    float g[8], c[8];
#pragma unroll
    for (int e = 0; e < 8; ++e) {
        g[e] = kg[o0 + cch * 8 + e];
        c[e] = kc[o0 + cch * 8 + e];
    }
    const short* yb = y + ((size_t)n * HW + p0) * COUT + o0;
#pragma unroll
    for (int j = 0; j < 2; ++j) {
        int pi = (t >> 3) + 32 * j;
        short8 sv = *(const short8*)&yb[(size_t)pi * COUT + cch * 8];
#pragma unroll
        for (int e = 0; e < 8; ++e)
            lds[pi * 65 + cch * 8 + e] = fmaxf(g[e] * (float)sv[e] + c[e], 0.f);
    }
    __syncthreads();
    float* ob = out + ((size_t)n * COUT + o0) * HW + p0;
    int pq = t & 15;       // 16 float4 = 64 pixels
    int ch = t >> 4;       // 16 channels per round
#pragma unroll
    for (int r = 0; r < 4; ++r) {
        int cr = ch + 16 * r;
        floatx4 v;
#pragma unroll
        for (int e = 0; e < 4; ++e) v[e] = lds[(pq * 4 + e) * 65 + cr];
        *(floatx4*)&ob[(size_t)cr * HW + pq * 4] = v;
    }
}

// ---------------------------------------------------------------------------
extern "C" void kernel_launch(void* const* d_in, const int* in_sizes, int n_in,
                              void* d_out, int out_size, void* d_ws, size_t ws_size,
                              hipStream_t stream) {
    const float* x     = (const float*)d_in[0];   // [32,256,56,56]
    const float* w     = (const float*)d_in[1];   // [256,256,3,3]
    const float* gamma = (const float*)d_in[2];   // [256]
    const float* beta  = (const float*)d_in[3];   // [256]
    float* out = (float*)d_out;

    char* ws = (char*)d_ws;
    size_t off = 0;
    i8* xs  = (i8*)(ws + off);    off += (size_t)BATCH * PPIX * CIN;               // 27.6 MB
    i8* bfr = (i8*)(ws + off);    off += (size_t)COUT * KTOT;                      // 0.59 MB
    short* y = (short*)(ws + off); off += (size_t)NPIX * COUT * sizeof(short);     // 51.4 MB
    float* scale   = (float*)(ws + off); off += 1024;
    float* bnsum   = (float*)(ws + off); off += 1024;
    float* bnsumsq = (float*)(ws + off); off += 1024;
    float* kg      = (float*)(ws + off); off += 1024;
    float* kc      = (float*)(ws + off); off += 1024;

    hipLaunchKernelGGL(prep_w, dim3(COUT), dim3(256), 0, stream, w, bfr, scale, bnsum, bnsumsq);
    hipLaunchKernelGGL(zero_border, dim3(BATCH * PH), dim3(256), 0, stream, xs);
    hipLaunchKernelGGL(binarize, dim3(HW / 64, CIN / 64, BATCH), dim3(256), 0, stream, x, xs);
    hipLaunchKernelGGL(conv_gemm, dim3(NPIX / 128, 2), dim3(256), 0, stream,
                       xs, bfr, y, bnsum, bnsumsq);
    hipLaunchKernelGGL(coeff, dim3(1), dim3(256), 0, stream,
                       bnsum, bnsumsq, scale, gamma, beta, kg, kc);
    hipLaunchKernelGGL(bn_out, dim3(HW / 64, COUT / 64, BATCH), dim3(256), 0, stream,
                       y, kg, kc, out);
}